// Round 12
// baseline (165.025 us; speedup 1.0000x reference)
//
#include <hip/hip_runtime.h>
#include <hip/hip_bf16.h>
#include <string.h>

typedef __attribute__((ext_vector_type(8))) short bf16x8;
typedef __attribute__((ext_vector_type(4))) float f32x4;

namespace {
constexpr int B = 8, H = 128, W = 128, C = 128;
constexpr int NOFF = 81;
constexpr int ROWS = 4;    // output rows per block
constexpr int WCOLS = 16;  // output cols per block (= MFMA tile m)
constexpr int NT = 512;    // 8 waves: (row r, dy-half hh)
}

__device__ inline unsigned bf2pack(float a, float b) {
  // RTNE fp32->bf16 pair via v_cvt_pk_bf16_f32 (a = low half)
  __hip_bfloat162 h = __float22bfloat162_rn(float2{a, b});
  unsigned r;
  memcpy(&r, &h, sizeof(r));
  return r;
}

__device__ __forceinline__ f32x4 mfma16(bf16x8 a, bf16x8 b, f32x4 c) {
  return __builtin_amdgcn_mfma_f32_16x16x32_bf16(a, b, c, 0, 0, 0);
}

__global__ __launch_bounds__(NT, 3) void costvol_kernel(
    const float* __restrict__ F1, const float* __restrict__ F2,
    const float* __restrict__ zpad, float* __restrict__ out)
{
  // No LDS. B-fragments load straight from global (L2/L3-resident) into
  // registers; OOB (s,t) pointers redirect into a zeroed scratch page.
  const int lin  = blockIdx.x;
  const int b    = lin & 7;          // one batch per XCD
  const int tile = lin >> 3;         // 0..255
  const int rt   = tile & 31;        // rt fastest: halo rows reuse in L2
  const int wt   = tile >> 5;        // 0..7
  const int h0   = rt * ROWS;
  const int wb0  = wt * WCOLS;

  const int tid  = threadIdx.x;
  const int wv   = tid >> 6;
  const int r    = wv >> 1;          // output row in tile (0..3)
  const int hh   = wv & 1;           // dy-half: 0 -> dy 0..4, 1 -> dy 4..8
  const int lane = tid & 63;
  const int j    = lane & 15;        // MFMA m/n index
  const int kq   = lane >> 4;        // k-quarter

  // ---- F1 A-fragments: direct global, prescaled by 1/128 (exact in bf16)
  const float* f1p = F1 + (((size_t)b * H + h0 + r) * W + wb0 + j) * C + kq * 8;
  float4 u0[4], u1[4];
#pragma unroll
  for (int kk = 0; kk < 4; ++kk) {
    u0[kk] = *reinterpret_cast<const float4*>(f1p + kk * 32);
    u1[kk] = *reinterpret_cast<const float4*>(f1p + kk * 32 + 4);
  }

  // ---- per-(s,t) B base pointers; OOB -> zeroed scratch (loads return 0)
  // dy = hh*4 + s; fy = h0 - 4 + r + dy; fx = wb0 - 4 + j + 16t
  const float* pB[5][2];
  const int rybase = r + hh * 4;
#pragma unroll
  for (int s = 0; s < 5; ++s) {
    const int fy = h0 - 4 + rybase + s;
#pragma unroll
    for (int t = 0; t < 2; ++t) {
      const int fx = wb0 - 4 + j + 16 * t;
      const bool ok = ((unsigned)fy < 128u) && ((unsigned)fx < 128u);
      pB[s][t] = ok ? (F2 + (((size_t)b * H + fy) * W + fx) * C) : zpad;
    }
  }

  bf16x8 afrag[4];
  constexpr float S = 0.0078125f;  // 1/128
#pragma unroll
  for (int kk = 0; kk < 4; ++kk) {
    uint4 q;
    q.x = bf2pack(u0[kk].x * S, u0[kk].y * S);
    q.y = bf2pack(u0[kk].z * S, u0[kk].w * S);
    q.z = bf2pack(u1[kk].x * S, u1[kk].y * S);
    q.w = bf2pack(u1[kk].z * S, u1[kk].w * S);
    afrag[kk] = __builtin_bit_cast(bf16x8, q);
  }

  f32x4 acc[5][2];
#pragma unroll
  for (int s = 0; s < 5; ++s) { acc[s][0] = {0,0,0,0}; acc[s][1] = {0,0,0,0}; }

  // ---- main: 80 global_load_dwordx4 + 160 cvt_pk + 40 MFMA, fully static,
  // no barriers; compiler pipelines loads across (kk,s) steps.
#pragma unroll
  for (int kk = 0; kk < 4; ++kk) {
#pragma unroll
    for (int s = 0; s < 5; ++s) {
      const float* p0 = pB[s][0] + kk * 32 + kq * 8;
      const float* p1 = pB[s][1] + kk * 32 + kq * 8;
      const float4 x0 = *reinterpret_cast<const float4*>(p0);
      const float4 x1 = *reinterpret_cast<const float4*>(p0 + 4);
      const float4 y0 = *reinterpret_cast<const float4*>(p1);
      const float4 y1 = *reinterpret_cast<const float4*>(p1 + 4);
      uint4 q0, q1;
      q0.x = bf2pack(x0.x, x0.y); q0.y = bf2pack(x0.z, x0.w);
      q0.z = bf2pack(x1.x, x1.y); q0.w = bf2pack(x1.z, x1.w);
      q1.x = bf2pack(y0.x, y0.y); q1.y = bf2pack(y0.z, y0.w);
      q1.z = bf2pack(y1.x, y1.y); q1.w = bf2pack(y1.z, y1.w);
      acc[s][0] = mfma16(afrag[kk], __builtin_bit_cast(bf16x8, q0), acc[s][0]);
      acc[s][1] = mfma16(afrag[kk], __builtin_bit_cast(bf16x8, q1), acc[s][1]);
    }
  }

  // ---- epilogue: band extract, leaky_relu(0.1), store (r11-verified)
  // out idx = i*81 + dy*9 + dxi; i = kq*4+reg, dy = hh*4+s, dxi = j+16t-i
  float* lb = out + (((size_t)b * H + h0 + r) * W + wb0) * NOFF +
              kq * 320 + j + hh * 36;
#pragma unroll
  for (int t = 0; t < 2; ++t) {
#pragma unroll
    for (int reg = 0; reg < 4; ++reg) {
      const int dxl = j + 16 * t - kq * 4 - reg;  // lane-dependent dxi
      if ((unsigned)dxl <= 8u) {
#pragma unroll
        for (int s = 0; s < 5; ++s) {
          float m = acc[s][t][reg];                // already /128 via prescale
          m = fmaxf(m, 0.1f * m);                  // leaky_relu(0.1)
          lb[reg * 80 + 16 * t + s * 9] = m;       // const offsets fold to imm
        }
      }
    }
  }
}

extern "C" void kernel_launch(void* const* d_in, const int* in_sizes, int n_in,
                              void* d_out, int out_size, void* d_ws, size_t ws_size,
                              hipStream_t stream) {
  const float* F1 = (const float*)d_in[0];
  const float* F2 = (const float*)d_in[1];
  float* out = (float*)d_out;
  // 1 KB zero page for OOB-redirected loads (reads span <= 512 B).
  // Async memset on `stream` is graph-capture-safe (becomes a memset node).
  hipMemsetAsync(d_ws, 0, 1024, stream);
  const float* zpad = (const float*)d_ws;
  dim3 grid(B * (H / ROWS) * (W / WCOLS));  // 2048 blocks
  dim3 block(NT);                           // 512 threads = 8 waves
  hipLaunchKernelGGL(costvol_kernel, grid, block, 0, stream, F1, F2, zpad, out);
}

// Round 13
// 65.410 us; speedup vs baseline: 2.5229x; 2.5229x over previous
//
#include <hip/hip_runtime.h>
#include <hip/hip_bf16.h>
#include <string.h>

typedef __attribute__((ext_vector_type(8))) short bf16x8;
typedef __attribute__((ext_vector_type(4))) float f32x4;

namespace {
constexpr int B = 8, H = 128, W = 128, C = 128;
constexpr int NOFF = 81;
constexpr int ROWS = 4;            // output rows per block (1 per wave)
constexpr int WCOLS = 16;          // output cols per tile
constexpr int F2R = 12;            // staged F2 rows (4 + 2*4 halo)
constexpr int SREAL = 24;          // staged cols, fx = wb0-4 .. wb0+19
constexpr int NT = 256;            // 4 waves
constexpr int NLD = 9;             // (12*24*8)/256 slots per thread per slab
constexpr int KSTR = 768;          // shorts per 32-ch k-slab
constexpr int ROWSTR = 4 * KSTR;   // 3072 shorts per staged row (128 ch)
constexpr int BUFS = F2R * ROWSTR + 256;  // 37120 shorts/buffer (incl pad)
constexpr int NTILE = 8;           // wt walk 0..7
constexpr int SMEM_BYTES = 2 * BUFS * 2;  // 148480 B
}

__device__ inline unsigned bf2pack(float a, float b) {
  // RTNE fp32->bf16 pair via v_cvt_pk_bf16_f32 (a = low half)
  __hip_bfloat162 h = __float22bfloat162_rn(float2{a, b});
  unsigned r;
  memcpy(&r, &h, sizeof(r));
  return r;
}

__device__ __forceinline__ f32x4 mfma16(bf16x8 a, bf16x8 b, f32x4 c) {
  return __builtin_amdgcn_mfma_f32_16x16x32_bf16(a, b, c, 0, 0, 0);
}

__global__ __launch_bounds__(NT, 1) void costvol_kernel(
    const float* __restrict__ F1, const float* __restrict__ F2,
    float* __restrict__ out)
{
  extern __shared__ __align__(16) short sF2[];  // 2 x BUFS shorts (148.5 KB)

  const int lin = blockIdx.x;          // 256 blocks: 1 per CU
  const int b   = lin & 7;             // one batch per XCD
  const int rt  = lin >> 3;            // row tile (fixed per block)
  const int h0  = rt * ROWS;

  const int tid  = threadIdx.x;
  const int r    = tid >> 6;           // wave index = output row in tile
  const int lane = tid & 63;
  const int j    = lane & 15;          // MFMA m/n index
  const int kq   = lane >> 4;          // k-quarter

  // ---- tile-invariant staging decode. gofs(tile) = rbase + wt*2048.
  int rbase[NLD]; int lofs[NLD]; int sarr[NLD]; unsigned okyM = 0;
#pragma unroll
  for (int it = 0; it < NLD; ++it) {
    const int idx  = tid + it * NT;    // 0..2303
    const int kg   = idx & 7;
    const int slot = idx >> 3;         // 0..287 -> (ry, s)
    const int ry   = slot / SREAL;
    const int s    = slot - ry * SREAL;
    const int fy   = h0 - 4 + ry;
    const bool oky = (unsigned)fy < 128u;
    okyM |= (unsigned)oky << it;
    sarr[it]  = s;
    rbase[it] = ((b * H + (oky ? fy : 0)) * W + (s - 4)) * C + kg * 4;
    lofs[it]  = ry * ROWSTR + s * 32 + kg * 4;
  }
  // per-tile ok mask: oky && fx-in-range (fx OOB only at wt=0 (s<4), wt=7 (s>=20))
  auto okm_of = [&](int wt) -> unsigned {
    unsigned m = okyM;
    if (wt == 0) {
#pragma unroll
      for (int it = 0; it < NLD; ++it) if (sarr[it] < 4) m &= ~(1u << it);
    }
    if (wt == 7) {
#pragma unroll
      for (int it = 0; it < NLD; ++it) if (sarr[it] >= 20) m &= ~(1u << it);
    }
    return m;
  };

  const float* f1b = F1 + (((size_t)b * H + h0 + r) * W + j) * C + kq * 8;
  float* outb = out + (((size_t)b * H + h0 + r) * W) * NOFF + kq * 320 + j;

  float4 ldv[36];                  // in-flight F2 tile (4 slabs x 9)
  float4 fu0[4], fu1[4];           // in-flight F1
  bf16x8 afrag[4];
  unsigned okmN;

  auto issue_tile = [&](int wt) {
    okmN = okm_of(wt);
#pragma unroll
    for (int it = 0; it < NLD; ++it) {
      const int go = ((okmN >> it) & 1u) ? (rbase[it] + wt * 2048) : 0;
#pragma unroll
      for (int g = 0; g < 4; ++g) {
        ldv[g * 9 + it] = *reinterpret_cast<const float4*>(F2 + go + g * 32);
      }
    }
    const float* f1p = f1b + wt * 2048;
#pragma unroll
    for (int kk = 0; kk < 4; ++kk) {
      fu0[kk] = *reinterpret_cast<const float4*>(f1p + kk * 32);
      fu1[kk] = *reinterpret_cast<const float4*>(f1p + kk * 32 + 4);
    }
    __builtin_amdgcn_sched_barrier(0);  // loads issue here; must not sink
  };
  auto pack_tile = [&](int buf) {
    short* dst = sF2 + buf * BUFS;
#pragma unroll
    for (int it = 0; it < NLD; ++it) {
      const bool ok = (okmN >> it) & 1u;
#pragma unroll
      for (int g = 0; g < 4; ++g) {
        uint2 p{0u, 0u};
        if (ok) {
          const float4 v = ldv[g * 9 + it];
          p.x = bf2pack(v.x, v.y);
          p.y = bf2pack(v.z, v.w);
        }
        *reinterpret_cast<uint2*>(dst + lofs[it] + g * KSTR) = p;
      }
    }
    constexpr float S = 0.0078125f;  // 1/128 prescale (exact in bf16)
#pragma unroll
    for (int kk = 0; kk < 4; ++kk) {
      uint4 q;
      q.x = bf2pack(fu0[kk].x * S, fu0[kk].y * S);
      q.y = bf2pack(fu0[kk].z * S, fu0[kk].w * S);
      q.z = bf2pack(fu1[kk].x * S, fu1[kk].y * S);
      q.w = bf2pack(fu1[kk].z * S, fu1[kk].w * S);
      afrag[kk] = __builtin_bit_cast(bf16x8, q);
    }
  };

  // ---- prologue: stage tile 0 into buf 0
  issue_tile(0);
  pack_tile(0);
  __syncthreads();

  // ---- persistent tile loop: compute T || (issue+pack T+1), 1 barrier/tile
  for (int tt = 0; tt < NTILE; ++tt) {
    if (tt < NTILE - 1) issue_tile(tt + 1);

    f32x4 acc[9][2];
#pragma unroll
    for (int d = 0; d < 9; ++d) { acc[d][0] = {0,0,0,0}; acc[d][1] = {0,0,0,0}; }

    const bf16x8 a0 = afrag[0], a1 = afrag[1], a2 = afrag[2], a3 = afrag[3];
    const short* bb = sF2 + (tt & 1) * BUFS + j * 32 + kq * 8;
#pragma unroll
    for (int kk = 0; kk < 4; ++kk) {
      const bf16x8 af = (kk == 0) ? a0 : (kk == 1) ? a1 : (kk == 2) ? a2 : a3;
      const short* bk = bb + kk * KSTR;
#pragma unroll
      for (int dy = 0; dy < 9; ++dy) {
        const short* brow = bk + (r + dy) * ROWSTR;
        const bf16x8 b0 = *reinterpret_cast<const bf16x8*>(brow);
        const bf16x8 b1 = *reinterpret_cast<const bf16x8*>(brow + 512);
        acc[dy][0] = mfma16(af, b0, acc[dy][0]);
        acc[dy][1] = mfma16(af, b1, acc[dy][1]);
      }
    }

    if (tt < NTILE - 1) pack_tile((tt + 1) & 1);  // overwrites afrag for T+1

    // epilogue tile tt: band extract, leaky_relu(0.1), store
    // out idx = i*81 + dy*9 + dxi; i = kq*4+reg, dxi = j+16t-i
    float* lb = outb + tt * (WCOLS * NOFF);  // wb0 = tt*16
#pragma unroll
    for (int t = 0; t < 2; ++t) {
#pragma unroll
      for (int reg = 0; reg < 4; ++reg) {
        const int dxl = j + 16 * t - kq * 4 - reg;
        if ((unsigned)dxl <= 8u) {
#pragma unroll
          for (int dy = 0; dy < 9; ++dy) {
            float m = acc[dy][t][reg];       // already /128 via prescale
            m = fmaxf(m, 0.1f * m);          // leaky_relu(0.1)
            lb[reg * 80 + 16 * t + dy * 9] = m;
          }
        }
      }
    }
    __syncthreads();  // the one barrier: buf[(tt+1)&1] packed by all waves
  }
}

extern "C" void kernel_launch(void* const* d_in, const int* in_sizes, int n_in,
                              void* d_out, int out_size, void* d_ws, size_t ws_size,
                              hipStream_t stream) {
  const float* F1 = (const float*)d_in[0];
  const float* F2 = (const float*)d_in[1];
  float* out = (float*)d_out;
  // 148.5 KB dynamic LDS (> 64 KB default cap) — raise the limit (idempotent,
  // host-side attribute; not a stream op, graph-capture-safe).
  hipFuncSetAttribute((const void*)costvol_kernel,
                      hipFuncAttributeMaxDynamicSharedMemorySize, SMEM_BYTES);
  dim3 grid(B * (H / ROWS));  // 256 blocks = 1 per CU, persistent over 8 tiles
  dim3 block(NT);             // 256 threads = 4 waves
  hipLaunchKernelGGL(costvol_kernel, grid, block, SMEM_BYTES, stream,
                     F1, F2, out);
}

// Round 14
// 47.088 us; speedup vs baseline: 3.5046x; 1.3891x over previous
//
#include <hip/hip_runtime.h>
#include <hip/hip_bf16.h>
#include <string.h>

typedef __attribute__((ext_vector_type(8))) short bf16x8;
typedef __attribute__((ext_vector_type(4))) float f32x4;

namespace {
constexpr int B = 8, H = 128, W = 128, C = 128;
constexpr int NOFF = 81;
constexpr int NT = 256;           // 4 waves, wave = output row in tile
constexpr int SREAL = 24;         // staged cols: fx = wb0-4 .. wb0+19
constexpr int NLD = 12;           // 16B loads/thread per 4-row stage
constexpr int KSTR = 768;         // shorts per 32-ch slab (24 cols x 32)
constexpr int ROWSTR = 3072;      // shorts per ring row (128 ch)
constexpr int RING = 12;          // ring rows (4 live + 8 halo)
constexpr int PADS = 256;         // b1-overread tail pad (discarded entries)
constexpr int RSHORTS = RING * ROWSTR + PADS;  // 37120 shorts = 74240 B
constexpr int NTILE = 8;          // 8 tiles x 4 rows = 32-row segment
}

__device__ inline unsigned bf2pack(float a, float b) {
  // RTNE fp32->bf16 pair via v_cvt_pk_bf16_f32 (a = low half)
  __hip_bfloat162 h = __float22bfloat162_rn(float2{a, b});
  unsigned r;
  memcpy(&r, &h, sizeof(r));
  return r;
}

__device__ __forceinline__ f32x4 mfma16(bf16x8 a, bf16x8 b, f32x4 c) {
  return __builtin_amdgcn_mfma_f32_16x16x32_bf16(a, b, c, 0, 0, 0);
}

__global__ __launch_bounds__(NT, 2) void costvol_kernel(
    const float* __restrict__ F1, const float* __restrict__ F2,
    float* __restrict__ out)
{
  // 12-row ring, per-row layout [kk][s][32ch] bf16 (r8-verified banking).
  __shared__ __align__(16) short ring[RSHORTS];  // 74,240 B -> 2 blocks/CU

  const int lin   = blockIdx.x;     // 256 blocks: b x wt x seg
  const int b     = lin & 7;        // one batch per XCD
  const int strip = lin >> 3;       // 0..31
  const int wt    = strip & 7;
  const int seg   = strip >> 3;     // 0..3 (32-row segments)
  const int hseg  = seg * 32;
  const int wb0   = wt * 16;

  const int tid  = threadIdx.x;
  const int r    = tid >> 6;        // wave = output row within tile
  const int lane = tid & 63;
  const int j    = lane & 15;       // MFMA m/n index
  const int kq   = lane >> 4;       // k-quarter

  float4 ldv[NLD];                  // in-flight 4-row F2 stage
  unsigned okm;                     // ok mask for the in-flight stage
  int fybc;                         // its base row

  // stage rows fyb..fyb+3: idx -> (rw 0..3, s 0..23, kg 0..31)
  auto issueF2 = [&](int fyb) {
    fybc = fyb;
    okm  = 0;
#pragma unroll
    for (int it = 0; it < NLD; ++it) {
      const int idx = tid + it * NT;      // 0..3071
      const int rw  = idx / 768;
      const int rem = idx - rw * 768;
      const int s   = rem >> 5;
      const int kg  = rem & 31;
      const int fy  = fyb + rw;
      const int fx  = wb0 - 4 + s;
      const bool ok = ((unsigned)fy < 128u) && ((unsigned)fx < 128u);
      okm |= (unsigned)ok << it;
      const int ga = ((b * H + (ok ? fy : 0)) * W + (ok ? fx : 0)) * C + kg * 4;
      ldv[it] = *reinterpret_cast<const float4*>(F2 + ga);
    }
    __builtin_amdgcn_sched_barrier(0);  // loads must issue here, not sink
  };
  auto packF2 = [&]() {
#pragma unroll
    for (int it = 0; it < NLD; ++it) {
      const int idx  = tid + it * NT;
      const int rw   = idx / 768;
      const int rem  = idx - rw * 768;
      const int s    = rem >> 5;
      const int kg   = rem & 31;
      const int slot = (unsigned)(fybc + rw + 48) % 12u;  // ring row
      const int lo   = slot * ROWSTR + (kg >> 3) * KSTR + s * 32 + (kg & 7) * 4;
      uint2 p{0u, 0u};
      if ((okm >> it) & 1u) {
        p.x = bf2pack(ldv[it].x, ldv[it].y);
        p.y = bf2pack(ldv[it].z, ldv[it].w);
      }
      *reinterpret_cast<uint2*>(&ring[lo]) = p;
    }
  };

  // F1: direct global -> afrag (prescaled 1/128), double set (tt parity)
  const float* f1b = F1 + (((size_t)b * H + hseg + r) * W + wb0 + j) * C + kq * 8;
  float4 u0[4], u1[4];
  auto issueF1 = [&](int tt) {
    const float* p = f1b + (size_t)tt * 4 * W * C;
#pragma unroll
    for (int kk = 0; kk < 4; ++kk) {
      u0[kk] = *reinterpret_cast<const float4*>(p + kk * 32);
      u1[kk] = *reinterpret_cast<const float4*>(p + kk * 32 + 4);
    }
  };
  bf16x8 afrag[2][4];
  constexpr float S = 0.0078125f;   // 1/128, exact in bf16
  auto packF1 = [&](int pp) {
#pragma unroll
    for (int kk = 0; kk < 4; ++kk) {
      uint4 q;
      q.x = bf2pack(u0[kk].x * S, u0[kk].y * S);
      q.y = bf2pack(u0[kk].z * S, u0[kk].w * S);
      q.z = bf2pack(u1[kk].x * S, u1[kk].y * S);
      q.w = bf2pack(u1[kk].z * S, u1[kk].w * S);
      afrag[pp][kk] = __builtin_bit_cast(bf16x8, q);
    }
  };

  // ---- prologue: fill ring rows hseg-4..hseg+7 (3 stages), F1 tile 0
  issueF2(hseg - 4);
  issueF1(0);
  packF2();
  issueF2(hseg);
  packF1(0);
  packF2();
  issueF2(hseg + 4);
  packF2();
  __syncthreads();

  // ---- persistent tile walk: 8 tiles of 4 rows, 4 fresh rows per tile
#pragma unroll
  for (int tt = 0; tt < NTILE; ++tt) {
    const int h0 = hseg + tt * 4;
    if (tt < NTILE - 1) {
      issueF2(h0 + 8);              // rows h0+8..h0+11 for tile tt+1
      issueF1(tt + 1);
    }

    int sofs[9];                    // ring byte offsets per dy (runtime r)
#pragma unroll
    for (int dy = 0; dy < 9; ++dy) {
      sofs[dy] = (int)((unsigned)(h0 - 4 + r + dy + 48) % 12u) * ROWSTR;
    }

    f32x4 acc[9][2];
#pragma unroll
    for (int d = 0; d < 9; ++d) { acc[d][0] = {0,0,0,0}; acc[d][1] = {0,0,0,0}; }

    const short* bb = ring + j * 32 + kq * 8;
    __builtin_amdgcn_s_setprio(1);
#pragma unroll
    for (int kk = 0; kk < 4; ++kk) {
      const bf16x8 af = afrag[tt & 1][kk];
      const short* bk = bb + kk * KSTR;
#pragma unroll
      for (int dy = 0; dy < 9; ++dy) {
        const short* brow = bk + sofs[dy];
        const bf16x8 b0 = *reinterpret_cast<const bf16x8*>(brow);
        const bf16x8 b1 = *reinterpret_cast<const bf16x8*>(brow + 512);
        acc[dy][0] = mfma16(af, b0, acc[dy][0]);
        acc[dy][1] = mfma16(af, b1, acc[dy][1]);
      }
    }
    __builtin_amdgcn_s_setprio(0);

    if (tt < NTILE - 1) {
      __syncthreads();              // all reads of overwritten rows done
      packF2();                     // fresh rows into freed ring slots
      packF1((tt + 1) & 1);
    }

    // epilogue tile tt: band extract (prescaled), leaky_relu(0.1), store
    // out idx = i*81 + dy*9 + dxi; i = kq*4+reg, dxi = j+16t-i
    float* lb = out + (((size_t)b * H + h0 + r) * W + wb0) * NOFF +
                kq * 320 + j;
#pragma unroll
    for (int t = 0; t < 2; ++t) {
#pragma unroll
      for (int reg = 0; reg < 4; ++reg) {
        const int dxl = j + 16 * t - kq * 4 - reg;
        if ((unsigned)dxl <= 8u) {
#pragma unroll
          for (int dy = 0; dy < 9; ++dy) {
            float m = acc[dy][t][reg];
            m = fmaxf(m, 0.1f * m);
            lb[reg * 80 + 16 * t + dy * 9] = m;
          }
        }
      }
    }
    if (tt < NTILE - 1) __syncthreads();  // ring updated for next tile
  }
}

extern "C" void kernel_launch(void* const* d_in, const int* in_sizes, int n_in,
                              void* d_out, int out_size, void* d_ws, size_t ws_size,
                              hipStream_t stream) {
  const float* F1 = (const float*)d_in[0];
  const float* F2 = (const float*)d_in[1];
  float* out = (float*)d_out;
  dim3 grid(256);   // 8 batches x 8 col-strips x 4 row-segments
  dim3 block(NT);   // 256 threads = 4 waves
  hipLaunchKernelGGL(costvol_kernel, grid, block, 0, stream, F1, F2, out);
}

// Round 15
// 42.714 us; speedup vs baseline: 3.8635x; 1.1024x over previous
//
#include <hip/hip_runtime.h>
#include <hip/hip_bf16.h>
#include <string.h>

typedef __attribute__((ext_vector_type(8))) short bf16x8;
typedef __attribute__((ext_vector_type(4))) float f32x4;

namespace {
constexpr int B = 8, H = 128, W = 128, C = 128;
constexpr int MO = 9, NOFF = 81;
constexpr int ROWS = 4;            // output rows per block (1 per wave)
constexpr int WCOLS = 16;          // output cols per block
constexpr int F2R = 12;            // staged F2 rows (4 + 2*4 halo)
constexpr int SREAL = 24;          // staged cols, fx = wb0-4 .. wb0+19
constexpr int NT = 256;            // 4 waves
constexpr int NLD = 9;             // float4 loads per thread per k-slab
constexpr int KSTR = SREAL * 32;   // 768 shorts per k-slab (32 ch)
constexpr int ROWSTR = 4 * KSTR;   // 3072 shorts per staged row (128 ch)
constexpr int PADS = 256;          // tail pad: b1 spill of (ry=11,kk=3) lands here
}

__device__ inline unsigned bf2pack(float a, float b) {
  // RTNE fp32->bf16 pair via v_cvt_pk_bf16_f32 (a = low half)
  __hip_bfloat162 h = __float22bfloat162_rn(float2{a, b});
  unsigned r;
  memcpy(&r, &h, sizeof(r));
  return r;
}

__device__ __forceinline__ f32x4 mfma16(bf16x8 a, bf16x8 b, f32x4 c) {
  return __builtin_amdgcn_mfma_f32_16x16x32_bf16(a, b, c, 0, 0, 0);
}

__global__ __launch_bounds__(NT, 2) void costvol_kernel(
    const float* __restrict__ F1, const float* __restrict__ F2,
    float* __restrict__ out)
{
  // Single buffer, whole 128-ch tile: [ry][kk][s][32ch] bf16 = 74,240 B.
  __shared__ __align__(16) short sF2[F2R * ROWSTR + PADS];

  const int lin  = blockIdx.x;
  // ---- convoy breaker: anti-phase the initially-resident block pairs.
  // Co-resident pair differs in bit0 (2k,2k+1 pairing) or bit8 (k,k+256);
  // xor covers both. ~6.5K cy = half of the ~13K cy block phase-sum.
  if (lin < 512 && ((lin ^ (lin >> 8)) & 1)) {
    __builtin_amdgcn_s_sleep(101);
  }

  const int b    = lin & 7;          // one batch per XCD
  const int tile = lin >> 3;         // 0..255
  const int rt   = tile & 31;        // rt fastest: halo rows reuse in L2
  const int wt   = tile >> 5;        // 0..7
  const int h0   = rt * ROWS;
  const int wb0  = wt * WCOLS;

  const int tid  = threadIdx.x;
  const int r    = tid >> 6;         // wave index = output row in tile
  const int lane = tid & 63;
  const int j    = lane & 15;        // MFMA m/n index
  const int kq   = lane >> 4;        // k-quarter within a slab

  // ---- loop-invariant staging decode (OOB -> offset 0, skipped at pack)
  int gofs[NLD]; int lofs[NLD]; unsigned okm = 0;
#pragma unroll
  for (int it = 0; it < NLD; ++it) {
    const int idx  = tid + it * NT;   // 0..2303
    const int kg   = idx & 7;         // channel-quad within slab
    const int slot = idx >> 3;        // 0..287 -> (ry, s)
    const int ry   = slot / SREAL;
    const int s    = slot - ry * SREAL;
    const int fy   = h0 - 4 + ry;
    const int fx   = wb0 - 4 + s;
    const bool ok  = ((unsigned)fy < 128u) && ((unsigned)fx < 128u);
    okm |= (unsigned)ok << it;
    gofs[it] = ok ? (((b * H + fy) * W + fx) * C + kg * 4) : 0;
    lofs[it] = ry * ROWSTR + s * 32 + kg * 4;
  }

  auto issue = [&](int g, float4* ld) {
#pragma unroll
    for (int it = 0; it < NLD; ++it) {
      ld[it] = *reinterpret_cast<const float4*>(F2 + gofs[it] + g * 32);
    }
    __builtin_amdgcn_sched_barrier(0);  // loads must issue here, not sink
  };
  auto pack = [&](int g, const float4* ld) {
#pragma unroll
    for (int it = 0; it < NLD; ++it) {
      if ((okm >> it) & 1u) {
        uint2 p;
        p.x = bf2pack(ld[it].x, ld[it].y);
        p.y = bf2pack(ld[it].z, ld[it].w);
        *reinterpret_cast<uint2*>(&sF2[lofs[it] + g * KSTR]) = p;
      }
    }
  };

  // ---- rolling staging pipeline: 2 groups in flight, 4 slabs total
  float4 ldA[NLD], ldB[NLD];
  issue(0, ldA);
  issue(1, ldB);
  // zero OOB slots (all 4 slabs) while g0 is in flight
#pragma unroll
  for (int it = 0; it < NLD; ++it) {
    if (!((okm >> it) & 1u)) {
#pragma unroll
      for (int g = 0; g < 4; ++g) {
        *reinterpret_cast<uint2*>(&sF2[lofs[it] + g * KSTR]) = uint2{0u, 0u};
      }
    }
  }
  pack(0, ldA);
  issue(2, ldA);
  pack(1, ldB);
  issue(3, ldB);
  pack(2, ldA);

  // F1 fragments direct from global (consumed after pack(3))
  const float* f1p = F1 + (((size_t)b * H + h0 + r) * W + wb0 + j) * C + kq * 8;
  float4 u0[4], u1[4];
#pragma unroll
  for (int kk = 0; kk < 4; ++kk) {
    u0[kk] = *reinterpret_cast<const float4*>(f1p + kk * 32);
    u1[kk] = *reinterpret_cast<const float4*>(f1p + kk * 32 + 4);
  }
  __builtin_amdgcn_sched_barrier(0);
  pack(3, ldB);

  // afrag with 1/128 prescale (exact exponent shift; epilogue mul removed)
  bf16x8 afrag[4];
  constexpr float S = 0.0078125f;
#pragma unroll
  for (int kk = 0; kk < 4; ++kk) {
    uint4 q;
    q.x = bf2pack(u0[kk].x * S, u0[kk].y * S);
    q.y = bf2pack(u0[kk].z * S, u0[kk].w * S);
    q.z = bf2pack(u1[kk].x * S, u1[kk].y * S);
    q.w = bf2pack(u1[kk].z * S, u1[kk].w * S);
    afrag[kk] = __builtin_bit_cast(bf16x8, q);
  }

  __syncthreads();  // the ONLY barrier

  // ---- compute burst: 72 ds_read_b128 + 72 MFMA
  f32x4 acc[9][2];
#pragma unroll
  for (int d = 0; d < 9; ++d) { acc[d][0] = {0,0,0,0}; acc[d][1] = {0,0,0,0}; }

  const short* bb = sF2 + j * 32 + kq * 8;
  __builtin_amdgcn_s_setprio(1);
#pragma unroll
  for (int kk = 0; kk < 4; ++kk) {
    const short* bk = bb + kk * KSTR;
#pragma unroll
    for (int dy = 0; dy < 9; ++dy) {
      const short* brow = bk + (r + dy) * ROWSTR;
      const bf16x8 b0 = *reinterpret_cast<const bf16x8*>(brow);
      const bf16x8 b1 = *reinterpret_cast<const bf16x8*>(brow + 512);
      acc[dy][0] = mfma16(afrag[kk], b0, acc[dy][0]);
      acc[dy][1] = mfma16(afrag[kk], b1, acc[dy][1]);
    }
  }
  __builtin_amdgcn_s_setprio(0);

  // ---- epilogue: band extract, leaky_relu(0.1), store
  // out idx = i*81 + dy*9 + dxi, i = kq*4+reg, dxi = j+16t-i
  float* lb = out + (((size_t)b * H + h0 + r) * W + wb0) * NOFF + kq * 320 + j;
#pragma unroll
  for (int t = 0; t < 2; ++t) {
#pragma unroll
    for (int reg = 0; reg < 4; ++reg) {
      const int dxl = j + 16 * t - kq * 4 - reg;  // lane-dependent dxi
      if ((unsigned)dxl <= 8u) {
#pragma unroll
        for (int dy = 0; dy < 9; ++dy) {
          float m = acc[dy][t][reg];               // already /128 via prescale
          m = fmaxf(m, 0.1f * m);                  // leaky_relu(0.1)
          lb[reg * 80 + 16 * t + dy * 9] = m;      // const offset folds to imm
        }
      }
    }
  }
}

extern "C" void kernel_launch(void* const* d_in, const int* in_sizes, int n_in,
                              void* d_out, int out_size, void* d_ws, size_t ws_size,
                              hipStream_t stream) {
  const float* F1 = (const float*)d_in[0];
  const float* F2 = (const float*)d_in[1];
  float* out = (float*)d_out;
  dim3 grid(B * (H / ROWS) * (W / WCOLS));  // 8 * 32 * 8 = 2048 blocks
  dim3 block(NT);                           // 256 threads = 4 waves
  hipLaunchKernelGGL(costvol_kernel, grid, block, 0, stream, F1, F2, out);
}